// Round 1
// baseline (186.815 us; speedup 1.0000x reference)
//
#include <hip/hip_runtime.h>

// Problem constants (reference: B=8, N=4096, F=1024, C=64)
#define B_  8
#define N_  4096
#define F_  1024
#define C_  64
#define TN  128        // rows per block tile
#define FC  32         // K-chunk (f) per iteration
#define PAD 36         // padded LDS stride (floats): 36*4=144B, 16B-aligned, breaks bank aliasing
#define NB  (N_ / TN)  // 32 row-tiles per (input,batch)

// K1: fp32 scores GEMM (x[b, n0:n0+128, :] @ W^T), fused per-block argmax partials.
// Thread map: tid = rg*8 + cg; rg in [0,32) owns 4 consecutive rows, cg in [0,8)
// owns 8 classes strided by 8 (c = cg + 8k) for conflict-free broadcast LDS reads.
__global__ __launch_bounds__(256, 2) void score_partial_kernel(
    const float* __restrict__ x1, const float* __restrict__ x2,
    const float* __restrict__ W,
    float* __restrict__ pmax, int* __restrict__ pidx)
{
    __shared__ float Xl[TN][PAD];   // 18 KiB
    __shared__ float Wl[C_][PAD];   //  9 KiB
    __shared__ float rs[C_][32];    //  8 KiB
    __shared__ int   ri[C_][32];    //  8 KiB

    const int tid = threadIdx.x;
    const int nb  = blockIdx.x;    // 0..31
    const int b   = blockIdx.y;    // 0..7
    const int inp = blockIdx.z;    // 0..1
    const float* __restrict__ x = inp ? x2 : x1;
    const int n0 = nb * TN;
    const float* __restrict__ xbase = x + ((size_t)b * N_ + n0) * F_;

    const int rg = tid >> 3;   // 0..31  (4 rows each)
    const int cg = tid & 7;    // 0..7   (classes cg + 8k)

    float acc[4][8];
    #pragma unroll
    for (int i = 0; i < 4; ++i)
        #pragma unroll
        for (int k = 0; k < 8; ++k) acc[i][k] = 0.0f;

    for (int kc = 0; kc < F_ / FC; ++kc) {
        const int f0 = kc * FC;
        // stage X tile chunk: 128 rows x 32 floats = 1024 float4, 4 per thread
        #pragma unroll
        for (int j = 0; j < 4; ++j) {
            int li  = tid + 256 * j;
            int row = li >> 3, q = li & 7;
            float4 v = *(const float4*)(xbase + (size_t)row * F_ + f0 + q * 4);
            *(float4*)&Xl[row][q * 4] = v;
        }
        // stage W chunk: 64 rows x 32 floats = 512 float4, 2 per thread
        #pragma unroll
        for (int j = 0; j < 2; ++j) {
            int li = tid + 256 * j;
            int c  = li >> 3, q = li & 7;
            float4 v = *(const float4*)(W + (size_t)c * F_ + f0 + q * 4);
            *(float4*)&Wl[c][q * 4] = v;
        }
        __syncthreads();

        #pragma unroll
        for (int g = 0; g < 8; ++g) {     // 4 f-values per step
            float4 xa[4], wb[8];
            #pragma unroll
            for (int i = 0; i < 4; ++i) xa[i] = *(const float4*)&Xl[rg * 4 + i][g * 4];
            #pragma unroll
            for (int k = 0; k < 8; ++k) wb[k] = *(const float4*)&Wl[cg + 8 * k][g * 4];
            #pragma unroll
            for (int i = 0; i < 4; ++i)
                #pragma unroll
                for (int k = 0; k < 8; ++k) {
                    float a = acc[i][k];
                    a = fmaf(xa[i].x, wb[k].x, a);
                    a = fmaf(xa[i].y, wb[k].y, a);
                    a = fmaf(xa[i].z, wb[k].z, a);
                    a = fmaf(xa[i].w, wb[k].w, a);
                    acc[i][k] = a;
                }
        }
        __syncthreads();
    }

    // per-thread argmax over its 4 rows (ascending i, strict > => first-max wins)
    #pragma unroll
    for (int k = 0; k < 8; ++k) {
        float m = acc[0][k]; int mi = 0;
        #pragma unroll
        for (int i = 1; i < 4; ++i)
            if (acc[i][k] > m) { m = acc[i][k]; mi = i; }
        rs[cg + 8 * k][rg] = m;
        ri[cg + 8 * k][rg] = n0 + rg * 4 + mi;
    }
    __syncthreads();

    // cross-thread reduce: one thread per class, ascending rg (=> ascending n)
    if (tid < C_) {
        const int c = tid;
        float m = rs[c][0]; int mi = ri[c][0];
        #pragma unroll 4
        for (int r = 1; r < 32; ++r) {
            float v = rs[c][r];
            if (v > m) { m = v; mi = ri[c][r]; }
        }
        const int o = ((inp * B_ + b) * NB + nb) * C_ + c;
        pmax[o] = m; pidx[o] = mi;
    }
}

// K2: one block per (inp,b,c): reduce 32 partials (score desc, idx asc), copy row.
__global__ __launch_bounds__(256) void gather_kernel(
    const float* __restrict__ x1, const float* __restrict__ x2,
    const float* __restrict__ pmax, const int* __restrict__ pidx,
    float* __restrict__ out)
{
    const int blk = blockIdx.x;         // 0..1023
    const int c   = blk & 63;
    const int b   = (blk >> 6) & 7;
    const int inp = blk >> 9;
    const int tid = threadIdx.x;
    __shared__ int srow;

    if (tid < 32) {
        const int o = ((inp * B_ + b) * NB + tid) * C_ + c;
        float m  = pmax[o];
        int   mi = pidx[o];
        #pragma unroll
        for (int off = 16; off; off >>= 1) {
            float om = __shfl_down(m, off, 32);
            int   oi = __shfl_down(mi, off, 32);
            if (om > m || (om == m && oi < mi)) { m = om; mi = oi; }
        }
        if (tid == 0) srow = mi;
    }
    __syncthreads();

    const int row = srow;
    const float* __restrict__ x = inp ? x2 : x1;
    const float4* __restrict__ src = (const float4*)(x + ((size_t)b * N_ + row) * F_);
    float4* __restrict__ dst = (float4*)(out + ((size_t)inp * B_ * C_ + (size_t)b * C_ + c) * F_);
    dst[tid] = src[tid];   // 256 threads * 16B = 4 KiB row
}

extern "C" void kernel_launch(void* const* d_in, const int* in_sizes, int n_in,
                              void* d_out, int out_size, void* d_ws, size_t ws_size,
                              hipStream_t stream) {
    const float* x1 = (const float*)d_in[0];
    const float* x2 = (const float*)d_in[1];
    const float* W  = (const float*)d_in[2];
    // d_in[3] is the bias: constant per class => cannot change the argmax. Skipped.

    float* pmax = (float*)d_ws;                                  // 2*8*32*64 floats = 128 KiB
    int*   pidx = (int*)((char*)d_ws + (size_t)2 * B_ * NB * C_ * sizeof(float));

    dim3 g1(NB, B_, 2);
    score_partial_kernel<<<g1, 256, 0, stream>>>(x1, x2, W, pmax, pidx);
    gather_kernel<<<2 * B_ * C_, 256, 0, stream>>>(x1, x2, pmax, pidx, (float*)d_out);
}

// Round 2
// 70.951 us; speedup vs baseline: 2.6330x; 2.6330x over previous
//
#include <hip/hip_runtime.h>

// Problem constants (reference: B=8, N=4096, F=1024, C=64)
#define B_   8
#define N_   4096
#define F_   1024
#define C_   64
#define TN   128          // rows per block tile
#define KC   64           // K (f) chunk per staging iteration
#define NB   (N_ / TN)    // 32 row-tiles per (input,batch)
#define MARGIN 0.02f      // >= 30x the bf16-split score error bound (~3e-4)

typedef __attribute__((ext_vector_type(8))) short bhalf8;   // 8 bf16 = 4 VGPRs (MFMA A/B frag)
typedef __attribute__((ext_vector_type(4))) float f32x4;    // MFMA C/D frag
typedef __attribute__((ext_vector_type(4))) unsigned short us4;

__device__ __forceinline__ unsigned short f2bf_rne(float x) {
    unsigned u = __builtin_bit_cast(unsigned, x);
    u += 0x7fffu + ((u >> 16) & 1u);          // round-to-nearest-even
    return (unsigned short)(u >> 16);
}
__device__ __forceinline__ float bf2f(unsigned short h) {
    unsigned u = ((unsigned)h) << 16;
    return __builtin_bit_cast(float, u);
}

#define LEXGT(a, ai, b, bi) ((a) > (b) || ((a) == (b) && (ai) < (bi)))
// insert (vv,nn) into sorted top-3 (v0,i0)>=(v1,i1)>=(v2,i2)
#define INSERT3(vv, nn)                                                   \
    do {                                                                  \
        float _v = (vv); int _n = (nn);                                   \
        if (LEXGT(_v, _n, v0, i0)) { v2=v1; i2=i1; v1=v0; i1=i0; v0=_v; i0=_n; } \
        else if (LEXGT(_v, _n, v1, i1)) { v2=v1; i2=i1; v1=_v; i1=_n; }   \
        else if (LEXGT(_v, _n, v2, i2)) { v2=_v; i2=_n; }                 \
    } while (0)

// K1: bf16-split MFMA GEMM (scores = x @ W^T), fused per-block per-class top-3.
// Block: 128 rows x 64 classes. 4 waves, each wave 32 rows x 64 classes
// (2 m-tiles x 4 n-tiles of 16x16x32 MFMA, 3 split passes each).
// LDS planes (bytes): Xh[128][128] @0, Xl @16384, Wh[64][128] @32768, Wl @40960.
// XOR swizzle ^((row&7)<<4) on the 128B row breaks the stride-128 bank conflict.
__global__ __launch_bounds__(256, 2) void score_top3_kernel(
    const float* __restrict__ x1, const float* __restrict__ x2,
    const float* __restrict__ W,
    float* __restrict__ pv, int* __restrict__ pi)
{
    __shared__ __align__(16) char lds[49152];
    __shared__ float tv[4][C_][3];
    __shared__ int   ti[4][C_][3];

    const int tid  = threadIdx.x;
    const int nb   = blockIdx.x;   // 0..31
    const int b    = blockIdx.y;   // 0..7
    const int inp  = blockIdx.z;   // 0..1
    const int n0   = nb * TN;
    const float* __restrict__ x = inp ? x2 : x1;
    const float* __restrict__ xbase = x + ((size_t)b * N_ + n0) * F_;

    const int lane = tid & 63;
    const int w    = tid >> 6;       // wave 0..3
    const int rsel = lane & 15;      // row-within-tile (A) / class-within-tile (B)
    const int g    = lane >> 4;      // k-group 0..3
    const int swz  = (rsel & 7) << 4;

    f32x4 acc[2][4];
    #pragma unroll
    for (int mt = 0; mt < 2; ++mt)
        #pragma unroll
        for (int nt = 0; nt < 4; ++nt) acc[mt][nt] = (f32x4){0.f, 0.f, 0.f, 0.f};

    for (int kc = 0; kc < F_ / KC; ++kc) {
        const int f0 = kc * KC;
        // ---- load global fp32 (X: 128x64 = 8 f4/thread; W: 64x64 = 4 f4/thread)
        float4 xv[8], wv[4];
        #pragma unroll
        for (int j = 0; j < 8; ++j) {
            int li = tid + 256 * j, row = li >> 4, fq = li & 15;
            xv[j] = *(const float4*)(xbase + (size_t)row * F_ + f0 + fq * 4);
        }
        #pragma unroll
        for (int j = 0; j < 4; ++j) {
            int li = tid + 256 * j, c = li >> 4, fq = li & 15;
            wv[j] = *(const float4*)(W + (size_t)c * F_ + f0 + fq * 4);
        }
        // ---- convert to bf16 hi/lo, write swizzled LDS
        #pragma unroll
        for (int j = 0; j < 8; ++j) {
            int li = tid + 256 * j, row = li >> 4, fq = li & 15;
            float f[4] = {xv[j].x, xv[j].y, xv[j].z, xv[j].w};
            us4 hh, ll;
            #pragma unroll
            for (int e = 0; e < 4; ++e) {
                unsigned short h = f2bf_rne(f[e]);
                hh[e] = h;
                ll[e] = f2bf_rne(f[e] - bf2f(h));
            }
            int off = (row * 128 + fq * 8) ^ ((row & 7) << 4);
            *(us4*)(lds + off)         = hh;
            *(us4*)(lds + 16384 + off) = ll;
        }
        #pragma unroll
        for (int j = 0; j < 4; ++j) {
            int li = tid + 256 * j, c = li >> 4, fq = li & 15;
            float f[4] = {wv[j].x, wv[j].y, wv[j].z, wv[j].w};
            us4 hh, ll;
            #pragma unroll
            for (int e = 0; e < 4; ++e) {
                unsigned short h = f2bf_rne(f[e]);
                hh[e] = h;
                ll[e] = f2bf_rne(f[e] - bf2f(h));
            }
            int off = (c * 128 + fq * 8) ^ ((c & 7) << 4);
            *(us4*)(lds + 32768 + off) = hh;
            *(us4*)(lds + 40960 + off) = ll;
        }
        __syncthreads();

        // ---- MFMA: 2 k-steps of 32, per step 12 ds_read_b128 + 24 MFMA
        #pragma unroll
        for (int ks = 0; ks < 2; ++ks) {
            bhalf8 ah[2], al[2], bh[4], bl[4];
            #pragma unroll
            for (int mt = 0; mt < 2; ++mt) {
                int arow = w * 32 + mt * 16 + rsel;
                int off = (arow * 128 + ks * 64 + g * 16) ^ swz;
                ah[mt] = *(const bhalf8*)(lds + off);
                al[mt] = *(const bhalf8*)(lds + 16384 + off);
            }
            #pragma unroll
            for (int nt = 0; nt < 4; ++nt) {
                int brow = nt * 16 + rsel;
                int off = (brow * 128 + ks * 64 + g * 16) ^ swz;
                bh[nt] = *(const bhalf8*)(lds + 32768 + off);
                bl[nt] = *(const bhalf8*)(lds + 40960 + off);
            }
            #pragma unroll
            for (int mt = 0; mt < 2; ++mt)
                #pragma unroll
                for (int nt = 0; nt < 4; ++nt) {
                    acc[mt][nt] = __builtin_amdgcn_mfma_f32_16x16x32_bf16(ah[mt], bh[nt], acc[mt][nt], 0, 0, 0);
                    acc[mt][nt] = __builtin_amdgcn_mfma_f32_16x16x32_bf16(ah[mt], bl[nt], acc[mt][nt], 0, 0, 0);
                    acc[mt][nt] = __builtin_amdgcn_mfma_f32_16x16x32_bf16(al[mt], bh[nt], acc[mt][nt], 0, 0, 0);
                }
        }
        __syncthreads();
    }

    // ---- per-class top-3. D layout: col=lane&15 (class), row=4*(lane>>4)+r.
    #pragma unroll
    for (int nt = 0; nt < 4; ++nt) {
        float v0 = -3.4e38f, v1 = -3.4e38f, v2 = -3.4e38f;
        int   i0 = 0x7fffffff, i1 = 0x7fffffff, i2 = 0x7fffffff;
        #pragma unroll
        for (int mt = 0; mt < 2; ++mt)
            #pragma unroll
            for (int r = 0; r < 4; ++r) {
                int n = n0 + w * 32 + mt * 16 + 4 * g + r;
                INSERT3(acc[mt][nt][r], n);
            }
        // merge across the 4 lanes holding this class (xor 16, xor 32)
        #pragma unroll
        for (int d = 16; d <= 32; d <<= 1) {
            float u0 = __shfl_xor(v0, d), u1 = __shfl_xor(v1, d), u2 = __shfl_xor(v2, d);
            int   j0 = __shfl_xor(i0, d), j1 = __shfl_xor(i1, d), j2 = __shfl_xor(i2, d);
            INSERT3(u0, j0); INSERT3(u1, j1); INSERT3(u2, j2);
        }
        if (lane < 16) {
            int c = nt * 16 + lane;
            tv[w][c][0] = v0; tv[w][c][1] = v1; tv[w][c][2] = v2;
            ti[w][c][0] = i0; ti[w][c][1] = i1; ti[w][c][2] = i2;
        }
    }
    __syncthreads();

    if (tid < C_) {
        int c = tid;
        float v0 = tv[0][c][0], v1 = tv[0][c][1], v2 = tv[0][c][2];
        int   i0 = ti[0][c][0], i1 = ti[0][c][1], i2 = ti[0][c][2];
        #pragma unroll
        for (int ww = 1; ww < 4; ++ww) {
            INSERT3(tv[ww][c][0], ti[ww][c][0]);
            INSERT3(tv[ww][c][1], ti[ww][c][1]);
            INSERT3(tv[ww][c][2], ti[ww][c][2]);
        }
        int blk = ((inp * B_ + b) * NB + nb);
        pv[(blk * C_ + c) * 3 + 0] = v0; pi[(blk * C_ + c) * 3 + 0] = i0;
        pv[(blk * C_ + c) * 3 + 1] = v1; pi[(blk * C_ + c) * 3 + 1] = i1;
        pv[(blk * C_ + c) * 3 + 2] = v2; pi[(blk * C_ + c) * 3 + 2] = i2;
    }
}

// K2: one block per (inp,b,c). Global max over 32 block-top3s, collect
// candidates within MARGIN, exact fp32 dot rescue if >1, gather winning row.
__global__ __launch_bounds__(256) void select_gather_kernel(
    const float* __restrict__ x1, const float* __restrict__ x2,
    const float* __restrict__ W,
    const float* __restrict__ pv, const int* __restrict__ pi,
    float* __restrict__ out)
{
    const int c   = blockIdx.x;    // 0..63
    const int b   = blockIdx.y;    // 0..7
    const int inp = blockIdx.z;    // 0..1
    const int tid = threadIdx.x;

    __shared__ int   s_cnt;
    __shared__ int   s_cand[8];
    __shared__ float s_val[8];
    __shared__ float s_wsum[4];
    __shared__ int   s_win;

    if (tid == 0) s_cnt = 0;
    __syncthreads();

    if (tid < 64) {
        float m = -3.4e38f;
        if (tid < 32) {
            int blk = ((inp * B_ + b) * NB + tid);
            m = pv[(blk * C_ + c) * 3 + 0];      // block max (entry 0)
        }
        #pragma unroll
        for (int d = 32; d; d >>= 1) m = fmaxf(m, __shfl_xor(m, d));
        if (tid < 32) {
            int blk = ((inp * B_ + b) * NB + tid);
            #pragma unroll
            for (int k = 0; k < 3; ++k) {
                float v = pv[(blk * C_ + c) * 3 + k];
                if (v >= m - MARGIN) {
                    int p = atomicAdd(&s_cnt, 1);
                    if (p < 8) s_cand[p] = pi[(blk * C_ + c) * 3 + k];
                }
            }
        }
    }
    __syncthreads();

    const float* __restrict__ x = inp ? x2 : x1;
    const int ncand = min(s_cnt, 8);
    int winner;
    if (ncand == 1) {
        winner = s_cand[0];
    } else {
        for (int k = 0; k < ncand; ++k) {
            int n = s_cand[k];
            float4 xv = *(const float4*)(x + ((size_t)b * N_ + n) * F_ + tid * 4);
            float4 wv = *(const float4*)(W + (size_t)c * F_ + tid * 4);
            float p = xv.x * wv.x + xv.y * wv.y + xv.z * wv.z + xv.w * wv.w;
            #pragma unroll
            for (int d = 32; d; d >>= 1) p += __shfl_down(p, d);
            if ((tid & 63) == 0) s_wsum[tid >> 6] = p;
            __syncthreads();
            if (tid == 0) s_val[k] = s_wsum[0] + s_wsum[1] + s_wsum[2] + s_wsum[3];
            __syncthreads();
        }
        if (tid == 0) {
            float bv = s_val[0]; int bn = s_cand[0];
            for (int k = 1; k < ncand; ++k)
                if (s_val[k] > bv || (s_val[k] == bv && s_cand[k] < bn)) { bv = s_val[k]; bn = s_cand[k]; }
            s_win = bn;
        }
        __syncthreads();
        winner = s_win;
    }

    float4 v = *(const float4*)(x + ((size_t)b * N_ + winner) * F_ + tid * 4);
    *(float4*)(out + (((size_t)inp * B_ + b) * C_ + c) * F_ + tid * 4) = v;
}

extern "C" void kernel_launch(void* const* d_in, const int* in_sizes, int n_in,
                              void* d_out, int out_size, void* d_ws, size_t ws_size,
                              hipStream_t stream) {
    const float* x1 = (const float*)d_in[0];
    const float* x2 = (const float*)d_in[1];
    const float* W  = (const float*)d_in[2];
    // d_in[3] (bias) is constant per class -> cannot change the argmax. Skipped.

    float* pv = (float*)d_ws;                                   // 2*8*32*64*3 floats = 384 KiB
    int*   pi = (int*)((char*)d_ws + (size_t)2 * B_ * NB * C_ * 3 * sizeof(float));

    dim3 g1(NB, B_, 2);
    score_top3_kernel<<<g1, 256, 0, stream>>>(x1, x2, W, pv, pi);
    dim3 g2(C_, B_, 2);
    select_gather_kernel<<<g2, 256, 0, stream>>>(x1, x2, W, pv, pi, (float*)d_out);
}